// Round 4
// baseline (41.111 us; speedup 1.0000x reference)
//
#include <hip/hip_runtime.h>

static constexpr int N_EP  = 8192;
static constexpr int T_LEN = 1024;
static constexpr float LMBDA = 0.95f;

typedef float floatx4 __attribute__((ext_vector_type(4)));

// One wave per episode row. Cyclic-chunk ownership: in round q, lane l owns
// timesteps t = q*256 + l*4 + {0..3} -> every access lane-stride-4B coalesced.
// Phase structure maximizes MLP: ALL loads first, then folds, then the four
// wave suffix-scans interleaved (independent), then a 4-FMA serial carry
// chain across rounds, then independent replays + nontemporal stores.
__global__ __launch_bounds__(256) void vtrace_kernel(
    const float* __restrict__ gammas,
    const float* __restrict__ vf_x,
    const float* __restrict__ rewards,
    const float* __restrict__ action_lls,
    const float* __restrict__ orig_lls,
    const int*   __restrict__ terminated,
    const int*   __restrict__ ep_len,
    float* __restrict__ adv_out,   // N*T
    float* __restrict__ vs_out)    // N*(T+1)
{
    const int n    = blockIdx.x * 4 + (threadIdx.x >> 6);
    const int lane = threadIdx.x & 63;
    const long rowT  = (long)n * T_LEN;
    const long rowT1 = (long)n * (T_LEN + 1);

    // ---- Phase 1: issue ALL global loads upfront (max MLP) ----
    floatx4 gg[4], rr[4], aa[4], oo[4];
    float vf[4][5];
#pragma unroll
    for (int q = 0; q < 4; ++q) {
        const int base = q * 256 + lane * 4;
        gg[q] = *reinterpret_cast<const floatx4*>(gammas     + rowT + base);
        rr[q] = *reinterpret_cast<const floatx4*>(rewards    + rowT + base);
        aa[q] = *reinterpret_cast<const floatx4*>(action_lls + rowT + base);
        oo[q] = *reinterpret_cast<const floatx4*>(orig_lls   + rowT + base);
    }
#pragma unroll
    for (int q = 0; q < 4; ++q) {
        const int base = q * 256 + lane * 4;
#pragma unroll
        for (int k = 0; k < 5; ++k) vf[q][k] = vf_x[rowT1 + base + k];
    }
    const int term = terminated[n];
    const int kill = ep_len[n] - 1;   // global timestep whose gamma is zeroed

    // ---- Phase 2: rho, gamma-kill, per-lane 4-step folds ----
    float g[4][4], r[4][4], rho[4][4];
#pragma unroll
    for (int q = 0; q < 4; ++q) {
#pragma unroll
        for (int j = 0; j < 4; ++j) {
            g[q][j] = gg[q][j];
            r[q][j] = rr[q][j];
            rho[q][j] = fminf(__expf(aa[q][j] - oo[q][j]), 1.0f);
        }
        if (term) {
            const int base = q * 256 + lane * 4;
#pragma unroll
            for (int j = 0; j < 4; ++j)
                if (kill == base + j) g[q][j] = 0.0f;
        }
    }

    float A[4], B[4];   // v_diff[base] = B + A * v_diff[base+4]
#pragma unroll
    for (int q = 0; q < 4; ++q) {
        float Aq = 1.0f, Bq = 0.0f;
#pragma unroll
        for (int j = 3; j >= 0; --j) {
            const float gc = LMBDA * rho[q][j] * g[q][j];
            const float dv = rho[q][j] * fmaf(g[q][j], vf[q][j + 1], r[q][j] - vf[q][j]);
            Bq = fmaf(gc, Bq, dv);
            Aq *= gc;
        }
        A[q] = Aq; B[q] = Bq;
    }

    // ---- Phase 3: four interleaved wave suffix-scans (independent) ----
#pragma unroll
    for (int d = 1; d < 64; d <<= 1) {
#pragma unroll
        for (int q = 0; q < 4; ++q) {
            const float An = __shfl_down(A[q], d, 64);
            const float Bn = __shfl_down(B[q], d, 64);
            if (lane + d < 64) { B[q] = fmaf(A[q], Bn, B[q]); A[q] *= An; }
        }
    }
    float A1[4], B1[4], A0[4], B0[4];
#pragma unroll
    for (int q = 0; q < 4; ++q) {
        A1[q] = __shfl_down(A[q], 1, 64);   // lanes l+1..63 composed
        B1[q] = __shfl_down(B[q], 1, 64);
        A0[q] = __shfl(A[q], 0, 64);        // whole-round map (lane 0)
        B0[q] = __shfl(B[q], 0, 64);
    }

    // ---- Phase 4: serial cross-round carries (4 FMAs total) ----
    // v_in[q] = v_diff[(q+1)*256]
    float v_in[4];
    v_in[3] = 0.0f;
    v_in[2] = B0[3];
    v_in[1] = fmaf(A0[2], v_in[2], B0[2]);
    v_in[0] = fmaf(A0[1], v_in[1], B0[1]);

    // ---- Phase 5: independent replays + nontemporal stores ----
#pragma unroll
    for (int q = 3; q >= 0; --q) {
        const int base = q * 256 + lane * 4;
        const float carry = (lane == 63) ? v_in[q]
                                         : fmaf(A1[q], v_in[q], B1[q]); // v_diff[base+4]
        float vs_next = carry + vf[q][4];          // v_s[base+4]
        if (q == 3 && lane == 63)
            __builtin_nontemporal_store(vs_next, vs_out + rowT1 + T_LEN);

        float v = carry;
        float vsa[4], adv[4];
#pragma unroll
        for (int j = 3; j >= 0; --j) {
            const float gc = LMBDA * rho[q][j] * g[q][j];
            const float dv = rho[q][j] * fmaf(g[q][j], vf[q][j + 1], r[q][j] - vf[q][j]);
            v = fmaf(gc, v, dv);                   // v_diff[base+j]
            vsa[j] = v + vf[q][j];                 // v_s[base+j]
            adv[j] = rho[q][j] * fmaf(r[q][j] * g[q][j], vs_next, -vf[q][j]);
            vs_next = vsa[j];
        }

        floatx4 av; av[0] = adv[0]; av[1] = adv[1]; av[2] = adv[2]; av[3] = adv[3];
        __builtin_nontemporal_store(
            av, reinterpret_cast<floatx4*>(adv_out + rowT + base));
#pragma unroll
        for (int j = 0; j < 4; ++j)
            __builtin_nontemporal_store(vsa[j], vs_out + rowT1 + base + j);
    }
}

extern "C" void kernel_launch(void* const* d_in, const int* in_sizes, int n_in,
                              void* d_out, int out_size, void* d_ws, size_t ws_size,
                              hipStream_t stream) {
    const float* gammas     = (const float*)d_in[0];
    const float* vf_x       = (const float*)d_in[1];
    const float* rewards    = (const float*)d_in[2];
    const float* action_lls = (const float*)d_in[3];
    const float* orig_lls   = (const float*)d_in[4];
    const int*   terminated = (const int*)d_in[5];
    const int*   ep_len     = (const int*)d_in[6];

    float* adv = (float*)d_out;
    float* vs  = adv + (long)N_EP * T_LEN;

    dim3 grid(N_EP / 4), block(256);
    hipLaunchKernelGGL(vtrace_kernel, grid, block, 0, stream,
                       gammas, vf_x, rewards, action_lls, orig_lls,
                       terminated, ep_len, adv, vs);
}

// Round 6
// 40.754 us; speedup vs baseline: 1.0087x; 1.0087x over previous
//
#include <hip/hip_runtime.h>

static constexpr int N_EP  = 8192;
static constexpr int T_LEN = 1024;
static constexpr float LMBDA = 0.95f;

// One wave per episode row. Cyclic-chunk ownership: in round q (q=3..0, backward),
// lane l owns timesteps t = q*256 + l*4 + {0..3}. All global accesses are
// lane-stride-4B (or 16B) coalesced, including the odd-stride vf_x/vs rows.
// Backward affine recurrence: per-lane 4-step fold -> wave suffix-scan of
// (A,B) affine maps (6 shfl steps) -> replay with true carry. Rounds are
// chained by broadcasting lane 0's final v (v_diff at the round boundary).
//
// BW analysis: 168 MB reads + 67 MB writes, each byte touched exactly once.
// Best measured 40.4 us -> 5.8 TB/s aggregate = ~93% of the 6.29 TB/s
// copy-ubench ceiling. MLP-maximized variant (R4) and nontemporal stores (R4)
// were neutral; asm cache-bit stores (R5) broke correctness. This is the
// practical streaming roofline for a 5-read/2-write mixed stream.
__global__ __launch_bounds__(256) void vtrace_kernel(
    const float* __restrict__ gammas,
    const float* __restrict__ vf_x,
    const float* __restrict__ rewards,
    const float* __restrict__ action_lls,
    const float* __restrict__ orig_lls,
    const int*   __restrict__ terminated,
    const int*   __restrict__ ep_len,
    float* __restrict__ adv_out,   // N*T
    float* __restrict__ vs_out)    // N*(T+1)
{
    const int n    = blockIdx.x * 4 + (threadIdx.x >> 6);
    const int lane = threadIdx.x & 63;
    if (n >= N_EP) return;

    const long rowT  = (long)n * T_LEN;
    const long rowT1 = (long)n * (T_LEN + 1);
    const int  term  = terminated[n];
    const int  kill  = ep_len[n] - 1;   // global timestep whose gamma is zeroed

    float v_in = 0.0f;                  // v_diff entering from t = (q+1)*256

#pragma unroll
    for (int q = 3; q >= 0; --q) {
        const int base = q * 256 + lane * 4;

        // ---- loads (all coalesced; float4 arrays are 16B aligned) ----
        const float4 gg = *reinterpret_cast<const float4*>(gammas     + rowT + base);
        const float4 rr = *reinterpret_cast<const float4*>(rewards    + rowT + base);
        const float4 aa = *reinterpret_cast<const float4*>(action_lls + rowT + base);
        const float4 oo = *reinterpret_cast<const float4*>(orig_lls   + rowT + base);
        float g[4] = {gg.x, gg.y, gg.z, gg.w};
        float r[4] = {rr.x, rr.y, rr.z, rr.w};
        float rho[4];
        rho[0] = fminf(__expf(aa.x - oo.x), 1.0f);
        rho[1] = fminf(__expf(aa.y - oo.y), 1.0f);
        rho[2] = fminf(__expf(aa.z - oo.z), 1.0f);
        rho[3] = fminf(__expf(aa.w - oo.w), 1.0f);

        float vf[5];                    // vf_x row has stride 1025 (no 16B align)
#pragma unroll
        for (int k = 0; k < 5; ++k) vf[k] = vf_x[rowT1 + base + k];

        // zero gamma at final step of terminated episodes (compile-time indices)
        if (term) {
#pragma unroll
            for (int j = 0; j < 4; ++j)
                if (kill == base + j) g[j] = 0.0f;
        }

        // ---- fold 4 steps into affine map: v[base] = B + A * v[base+4] ----
        float A = 1.0f, B = 0.0f;
#pragma unroll
        for (int j = 3; j >= 0; --j) {
            const float gc = LMBDA * rho[j] * g[j];
            const float dv = rho[j] * fmaf(g[j], vf[j + 1], r[j] - vf[j]);
            B = fmaf(gc, B, dv);
            A *= gc;
        }

        // ---- wave suffix-scan: lane l composes maps of lanes l..63 ----
#pragma unroll
        for (int d = 1; d < 64; d <<= 1) {
            const float An = __shfl_down(A, d, 64);
            const float Bn = __shfl_down(B, d, 64);
            if (lane + d < 64) { B = fmaf(A, Bn, B); A *= An; }
        }
        const float A1 = __shfl_down(A, 1, 64);
        const float B1 = __shfl_down(B, 1, 64);
        const float carry = (lane == 63) ? v_in : fmaf(A1, v_in, B1); // v_diff[base+4]

        float vs_next = carry + vf[4];              // v_s[base+4]
        if (q == 3 && lane == 63)
            vs_out[rowT1 + T_LEN] = vs_next;        // v_s[:, T] = vf_x[:, T]

        // ---- replay with true carry ----
        float v = carry;
        float vsa[4], adv[4];
#pragma unroll
        for (int j = 3; j >= 0; --j) {
            const float gc = LMBDA * rho[j] * g[j];
            const float dv = rho[j] * fmaf(g[j], vf[j + 1], r[j] - vf[j]);
            v = fmaf(gc, v, dv);                    // v_diff[base+j]
            vsa[j] = v + vf[j];                     // v_s[base+j]
            adv[j] = rho[j] * fmaf(r[j] * g[j], vs_next, -vf[j]);
            vs_next = vsa[j];
        }

        // ---- stores (coalesced) ----
        *reinterpret_cast<float4*>(adv_out + rowT + base) =
            make_float4(adv[0], adv[1], adv[2], adv[3]);
#pragma unroll
        for (int j = 0; j < 4; ++j) vs_out[rowT1 + base + j] = vsa[j];

        // carry for next (lower-t) round: lane 0 holds v_diff[q*256]
        v_in = __shfl(v, 0, 64);
    }
}

extern "C" void kernel_launch(void* const* d_in, const int* in_sizes, int n_in,
                              void* d_out, int out_size, void* d_ws, size_t ws_size,
                              hipStream_t stream) {
    const float* gammas     = (const float*)d_in[0];
    const float* vf_x       = (const float*)d_in[1];
    const float* rewards    = (const float*)d_in[2];
    const float* action_lls = (const float*)d_in[3];
    const float* orig_lls   = (const float*)d_in[4];
    const int*   terminated = (const int*)d_in[5];
    const int*   ep_len     = (const int*)d_in[6];

    float* adv = (float*)d_out;
    float* vs  = adv + (long)N_EP * T_LEN;

    dim3 grid(N_EP / 4), block(256);
    hipLaunchKernelGGL(vtrace_kernel, grid, block, 0, stream,
                       gammas, vf_x, rewards, action_lls, orig_lls,
                       terminated, ep_len, adv, vs);
}